// Round 3
// baseline (261.321 us; speedup 1.0000x reference)
//
#include <hip/hip_runtime.h>

#define SEQ 4096
#define DM  2048
#define DH  128

typedef __attribute__((ext_vector_type(8))) short bf16x8;
typedef __attribute__((ext_vector_type(4))) short short4v;
typedef __attribute__((ext_vector_type(4))) float f32x4;

__device__ inline short f2bf(float f) {
    union { float f; unsigned u; } x; x.f = f;
    unsigned r = x.u + 0x7fffu + ((x.u >> 16) & 1u);
    return (short)(r >> 16);
}

// ---------------- W fp32 -> bf16 pre-convert. grid 768, block 256. Wbf[3][128][2048]
__global__ __launch_bounds__(256) void convw_kernel(
    const float* __restrict__ wq, const float* __restrict__ wk, const float* __restrict__ wv,
    short* __restrict__ Wbf)
{
    int idx = blockIdx.x * 256 + threadIdx.x;     // 196608 threads, 4 elems each
    int mat = idx >> 16;                          // 65536 float4-groups per matrix
    int off = (idx & 65535) * 4;
    const float* W = (mat == 0) ? wq : (mat == 1) ? wk : wv;
    float4 v = *reinterpret_cast<const float4*>(W + off);
    short4v s = { f2bf(v.x), f2bf(v.y), f2bf(v.z), f2bf(v.w) };
    *reinterpret_cast<short4v*>(Wbf + (size_t)mat * DH * DM + off) = s;
}

// ---------------- Projection: C = A @ W^T + b. grid (256, 3), block 256 (4 waves).
// Block: 16 rows x 128 cols; wave w owns cols [32w, 32w+32).
// NO LDS, NO barriers: A fragments loaded per-lane directly from global fp32
// (A[m=lane&15][k=(lane>>4)*8+j] layout), converted in-register; W fragments
// read as ready bf16 from Wbf (L1/L2-hot). 64 independent K-iterations.
__global__ __launch_bounds__(256) void proj_kernel(
    const float* __restrict__ inq, const float* __restrict__ ink, const float* __restrict__ inv,
    const short* __restrict__ Wbf,
    const float* __restrict__ bq, const float* __restrict__ bk, const float* __restrict__ bv,
    short* __restrict__ Qws, short* __restrict__ Kws, short* __restrict__ Vtws)
{
    const int mat = blockIdx.y;
    const float* A    = (mat == 0) ? inq : (mat == 1) ? ink : inv;
    const short* W    = Wbf + (size_t)mat * DH * DM;
    const float* bias = (mat == 0) ? bq : (mat == 1) ? bk : bv;

    const int tid  = threadIdx.x;
    const int lane = tid & 63;
    const int w    = tid >> 6;
    const int g    = lane >> 4;
    const int c16  = lane & 15;
    const int i0   = blockIdx.x * 16;

    const float* Arow = A + (size_t)(i0 + c16) * DM + g * 8;
    const short* W0   = W + (size_t)(w * 32 + c16) * DM + g * 8;
    const short* W1   = W0 + (size_t)16 * DM;

    f32x4 acc0 = {0.f, 0.f, 0.f, 0.f}, acc1 = {0.f, 0.f, 0.f, 0.f};

    #pragma unroll 4
    for (int kc = 0; kc < DM; kc += 32) {
        float4 a0 = *reinterpret_cast<const float4*>(Arow + kc);
        float4 a1 = *reinterpret_cast<const float4*>(Arow + kc + 4);
        bf16x8 w0 = *reinterpret_cast<const bf16x8*>(W0 + kc);
        bf16x8 w1 = *reinterpret_cast<const bf16x8*>(W1 + kc);
        bf16x8 af = { f2bf(a0.x), f2bf(a0.y), f2bf(a0.z), f2bf(a0.w),
                      f2bf(a1.x), f2bf(a1.y), f2bf(a1.z), f2bf(a1.w) };
        acc0 = __builtin_amdgcn_mfma_f32_16x16x32_bf16(af, w0, acc0, 0, 0, 0);
        acc1 = __builtin_amdgcn_mfma_f32_16x16x32_bf16(af, w1, acc1, 0, 0, 0);
    }

    const int col0 = w * 32 + c16, col1 = col0 + 16;
    const float b0 = bias[col0], b1 = bias[col1];
    if (mat < 2) {
        short* outp = (mat == 0) ? Qws : Kws;
        #pragma unroll
        for (int r = 0; r < 4; r++) {
            outp[(size_t)(i0 + g * 4 + r) * DH + col0] = f2bf(acc0[r] + b0);
            outp[(size_t)(i0 + g * 4 + r) * DH + col1] = f2bf(acc1[r] + b1);
        }
    } else {
        short4v s0, s1;
        #pragma unroll
        for (int r = 0; r < 4; r++) { s0[r] = f2bf(acc0[r] + b0); s1[r] = f2bf(acc1[r] + b1); }
        *reinterpret_cast<short4v*>(&Vtws[(size_t)col0 * SEQ + i0 + g * 4]) = s0;
        *reinterpret_cast<short4v*>(&Vtws[(size_t)col1 * SEQ + i0 + g * 4]) = s1;
    }
}

// ---------------- Flash attention, NS-way key split (NS = gridDim.y).
// grid (256, NS), block 64 (one wave). q-tile = 16 rows, j-tile = 64 keys.
__global__ __launch_bounds__(64) void flash_kernel(
    const short* __restrict__ Qws, const short* __restrict__ Kws, const short* __restrict__ Vtws,
    float* __restrict__ Opart, float* __restrict__ mpart, float* __restrict__ lpart)
{
    const int i  = blockIdx.x;
    const int h  = blockIdx.y;
    const int NS = gridDim.y;
    const int i0 = i * 16;
    const int lane = threadIdx.x;
    const int g = lane >> 4, c16 = lane & 15;

    __shared__ short Slds[16][72];

    bf16x8 qf[4];
    #pragma unroll
    for (int kk = 0; kk < 4; kk++)
        qf[kk] = *reinterpret_cast<const bf16x8*>(Qws + (size_t)(i0 + c16) * DH + kk * 32 + g * 8);

    float m[4], lsum[4];
    f32x4 O[8];
    #pragma unroll
    for (int r = 0; r < 4; r++) { m[r] = -__builtin_inff(); lsum[r] = 0.f; }
    #pragma unroll
    for (int c = 0; c < 8; c++) O[c] = (f32x4){0.f, 0.f, 0.f, 0.f};

    const int njt = i / 4 + 1;
    const float C = 0.03188448666f;            // log2(e)/sqrt(2048)

    for (int jt = h; jt < njt; jt += NS) {
        const int j0 = jt * 64;
        f32x4 S[4];
        #pragma unroll
        for (int t = 0; t < 4; t++) S[t] = (f32x4){0.f, 0.f, 0.f, 0.f};
        #pragma unroll
        for (int kk = 0; kk < 4; kk++) {
            #pragma unroll
            for (int t = 0; t < 4; t++) {
                bf16x8 kf = *reinterpret_cast<const bf16x8*>(
                    Kws + (size_t)(j0 + t * 16 + c16) * DH + kk * 32 + g * 8);
                S[t] = __builtin_amdgcn_mfma_f32_16x16x32_bf16(qf[kk], kf, S[t], 0, 0, 0);
            }
        }
        float s2[4][4];
        #pragma unroll
        for (int t = 0; t < 4; t++) {
            int key = j0 + t * 16 + c16;
            #pragma unroll
            for (int r = 0; r < 4; r++) {
                int q = i0 + g * 4 + r;
                s2[t][r] = (key > q) ? -__builtin_inff() : S[t][r] * C;
            }
        }
        float mnew[4], alpha[4];
        #pragma unroll
        for (int r = 0; r < 4; r++) {
            float rm = fmaxf(fmaxf(s2[0][r], s2[1][r]), fmaxf(s2[2][r], s2[3][r]));
            rm = fmaxf(rm, __shfl_xor(rm, 1));
            rm = fmaxf(rm, __shfl_xor(rm, 2));
            rm = fmaxf(rm, __shfl_xor(rm, 4));
            rm = fmaxf(rm, __shfl_xor(rm, 8));
            mnew[r] = fmaxf(m[r], rm);
            alpha[r] = exp2f(m[r] - mnew[r]);
            m[r] = mnew[r];
        }
        #pragma unroll
        for (int r = 0; r < 4; r++) {
            float ps = 0.f;
            #pragma unroll
            for (int t = 0; t < 4; t++) {
                float p = exp2f(s2[t][r] - mnew[r]);
                ps += p;
                Slds[g * 4 + r][t * 16 + c16] = f2bf(p);
            }
            ps += __shfl_xor(ps, 1);
            ps += __shfl_xor(ps, 2);
            ps += __shfl_xor(ps, 4);
            ps += __shfl_xor(ps, 8);
            lsum[r] = lsum[r] * alpha[r] + ps;
            #pragma unroll
            for (int c = 0; c < 8; c++) O[c][r] *= alpha[r];
        }
        #pragma unroll
        for (int kk2 = 0; kk2 < 2; kk2++) {
            bf16x8 pf = *reinterpret_cast<const bf16x8*>(&Slds[c16][kk2 * 32 + g * 8]);
            #pragma unroll
            for (int c = 0; c < 8; c++) {
                bf16x8 vf = *reinterpret_cast<const bf16x8*>(
                    Vtws + (size_t)(c * 16 + c16) * SEQ + j0 + kk2 * 32 + g * 8);
                O[c] = __builtin_amdgcn_mfma_f32_16x16x32_bf16(pf, vf, O[c], 0, 0, 0);
            }
        }
    }
    #pragma unroll
    for (int c = 0; c < 8; c++) {
        int col = c * 16 + c16;
        #pragma unroll
        for (int r = 0; r < 4; r++)
            Opart[((size_t)h * SEQ + i0 + g * 4 + r) * DH + col] = O[c][r];
    }
    if (c16 == 0) {
        #pragma unroll
        for (int r = 0; r < 4; r++) {
            mpart[h * SEQ + i0 + g * 4 + r] = m[r];
            lpart[h * SEQ + i0 + g * 4 + r] = lsum[r];
        }
    }
}

// ---------------- Merge NS split partials. grid 2048, block 256 (2 rows/block).
__global__ __launch_bounds__(256) void merge_kernel(
    const float* __restrict__ Opart, const float* __restrict__ mpart, const float* __restrict__ lpart,
    float* __restrict__ out, int NS)
{
    const int row = blockIdx.x * 2 + (threadIdx.x >> 7);
    const int col = threadIdx.x & 127;
    float mh[16];
    float M = -__builtin_inff();
    for (int hh = 0; hh < NS; hh++) {
        mh[hh] = mpart[hh * SEQ + row];
        M = fmaxf(M, mh[hh]);
    }
    float denom = 0.f, num = 0.f;
    for (int hh = 0; hh < NS; hh++) {
        float wgt = exp2f(mh[hh] - M);
        denom += lpart[hh * SEQ + row] * wgt;
        num   += Opart[((size_t)hh * SEQ + row) * DH + col] * wgt;
    }
    out[(size_t)row * DH + col] = num / denom;
}

extern "C" void kernel_launch(void* const* d_in, const int* in_sizes, int n_in,
                              void* d_out, int out_size, void* d_ws, size_t ws_size,
                              hipStream_t stream) {
    const float* inq = (const float*)d_in[0];
    const float* ink = (const float*)d_in[1];
    const float* inv = (const float*)d_in[2];
    const float* wq  = (const float*)d_in[3];
    const float* bq  = (const float*)d_in[4];
    const float* wk  = (const float*)d_in[5];
    const float* bk  = (const float*)d_in[6];
    const float* wv  = (const float*)d_in[7];
    const float* bv  = (const float*)d_in[8];

    const int NS = (ws_size >= (size_t)36 * 1024 * 1024) ? 16 : 8;

    char* ws = (char*)d_ws;
    short* Qws   = (short*)(ws);                         // 1 MB
    short* Kws   = (short*)(ws + (1u << 20));            // 1 MB
    short* Vtws  = (short*)(ws + (2u << 20));            // 1 MB (transposed [128][4096])
    short* Wbf   = (short*)(ws + (3u << 20));            // 1.5 MB (bf16 W, proj-only)
    float* Opart = (float*)(ws + (3u << 20));            // aliases Wbf: Wbf dead before flash
    float* mpart = (float*)(ws + (3u << 20) + (size_t)NS * SEQ * DH * 4);
    float* lpart = mpart + (size_t)NS * SEQ;

    convw_kernel<<<768, 256, 0, stream>>>(wq, wk, wv, Wbf);
    proj_kernel<<<dim3(256, 3), 256, 0, stream>>>(inq, ink, inv, Wbf, bq, bk, bv,
                                                  Qws, Kws, Vtws);
    flash_kernel<<<dim3(256, NS), 64, 0, stream>>>(Qws, Kws, Vtws, Opart, mpart, lpart);
    merge_kernel<<<2048, 256, 0, stream>>>(Opart, mpart, lpart, (float*)d_out, NS);
}

// Round 4
// 244.853 us; speedup vs baseline: 1.0673x; 1.0673x over previous
//
#include <hip/hip_runtime.h>

#define SEQ 4096
#define DM  2048
#define DH  128

typedef __attribute__((ext_vector_type(8))) short bf16x8;
typedef __attribute__((ext_vector_type(4))) short short4v;
typedef __attribute__((ext_vector_type(4))) float f32x4;

__device__ inline short f2bf(float f) {
    union { float f; unsigned u; } x; x.f = f;
    unsigned r = x.u + 0x7fffu + ((x.u >> 16) & 1u);
    return (short)(r >> 16);
}

// ---------------- W fp32 -> bf16 pre-convert. grid 768, block 256. Wbf[3][128][2048]
__global__ __launch_bounds__(256) void convw_kernel(
    const float* __restrict__ wq, const float* __restrict__ wk, const float* __restrict__ wv,
    short* __restrict__ Wbf)
{
    int idx = blockIdx.x * 256 + threadIdx.x;
    int mat = idx >> 16;
    int off = (idx & 65535) * 4;
    const float* W = (mat == 0) ? wq : (mat == 1) ? wk : wv;
    float4 v = *reinterpret_cast<const float4*>(W + off);
    short4v s = { f2bf(v.x), f2bf(v.y), f2bf(v.z), f2bf(v.w) };
    *reinterpret_cast<short4v*>(Wbf + (size_t)mat * DH * DM + off) = s;
}

// ---------------- Projection, split-K x2: partial = A[:,ks] @ W[:,ks]^T (+bias on s=0).
// grid (256, 3, 2), block 256 (4 waves). Block: 16 rows x 128 cols, K-range 1024.
// A staged in dbuf LDS with load->compute->store overlap; W read as bf16 frags (L2-hot).
__global__ __launch_bounds__(256, 6) void proj_kernel(
    const float* __restrict__ inq, const float* __restrict__ ink, const float* __restrict__ inv,
    const short* __restrict__ Wbf,
    const float* __restrict__ bq, const float* __restrict__ bk, const float* __restrict__ bv,
    float* __restrict__ Pqk, float* __restrict__ Pv)
{
    const int mat = blockIdx.y;
    const int s   = blockIdx.z;
    const float* A    = (mat == 0) ? inq : (mat == 1) ? ink : inv;
    const float* bias = (mat == 0) ? bq : (mat == 1) ? bk : bv;

    const int tid  = threadIdx.x;
    const int lane = tid & 63;
    const int w    = tid >> 6;
    const int g    = lane >> 4;
    const int c16  = lane & 15;
    const int i0   = blockIdx.x * 16;
    const int kb   = s * 1024;

    __shared__ short Alds[2][16][72];

    const int arow = tid >> 4, apos = tid & 15;
    const float* Aload = A + (size_t)(i0 + arow) * DM + kb + apos * 4;
    const short* W0 = Wbf + (size_t)mat * DH * DM + (size_t)(w * 32 + c16) * DM + kb + g * 8;
    const short* W1 = W0 + (size_t)16 * DM;

    f32x4 acc0 = {0.f, 0.f, 0.f, 0.f}, acc1 = {0.f, 0.f, 0.f, 0.f};

    auto store_lds = [&](int b, float4 v) {
        short4v sv = { f2bf(v.x), f2bf(v.y), f2bf(v.z), f2bf(v.w) };
        *reinterpret_cast<short4v*>(&Alds[b][arow][apos * 4]) = sv;
    };
    auto compute = [&](int b, int c) {
        const int ko = c * 64;
        #pragma unroll
        for (int kk = 0; kk < 2; kk++) {
            bf16x8 af = *reinterpret_cast<const bf16x8*>(&Alds[b][c16][kk * 32 + g * 8]);
            bf16x8 w0 = *reinterpret_cast<const bf16x8*>(W0 + ko + kk * 32);
            bf16x8 w1 = *reinterpret_cast<const bf16x8*>(W1 + ko + kk * 32);
            acc0 = __builtin_amdgcn_mfma_f32_16x16x32_bf16(af, w0, acc0, 0, 0, 0);
            acc1 = __builtin_amdgcn_mfma_f32_16x16x32_bf16(af, w1, acc1, 0, 0, 0);
        }
    };

    float4 v = *reinterpret_cast<const float4*>(Aload);
    store_lds(0, v);
    __syncthreads();
    // 16 chunks of 64 K, double-buffered, load issued BEFORE compute of prior chunk
    for (int c = 0; c < 16; c += 2) {
        float4 vn = *reinterpret_cast<const float4*>(Aload + (c + 1) * 64);
        compute(0, c);
        store_lds(1, vn);
        __syncthreads();
        if (c < 14) v = *reinterpret_cast<const float4*>(Aload + (c + 2) * 64);
        compute(1, c + 1);
        if (c < 14) store_lds(0, v);
        __syncthreads();
    }

    const int col0 = w * 32 + c16, col1 = col0 + 16;
    const float b0 = (s == 0) ? bias[col0] : 0.f;
    const float b1 = (s == 0) ? bias[col1] : 0.f;
    if (mat < 2) {
        float* outp = Pqk + ((size_t)(mat * 2 + s) * SEQ) * DH;
        #pragma unroll
        for (int r = 0; r < 4; r++) {
            outp[(size_t)(i0 + g * 4 + r) * DH + col0] = acc0[r] + b0;
            outp[(size_t)(i0 + g * 4 + r) * DH + col1] = acc1[r] + b1;
        }
    } else {
        float* outp = Pv + (size_t)s * DH * SEQ;
        float4 f0 = { acc0[0] + b0, acc0[1] + b0, acc0[2] + b0, acc0[3] + b0 };
        float4 f1 = { acc1[0] + b1, acc1[1] + b1, acc1[2] + b1, acc1[3] + b1 };
        *reinterpret_cast<float4*>(&outp[(size_t)col0 * SEQ + i0 + g * 4]) = f0;
        *reinterpret_cast<float4*>(&outp[(size_t)col1 * SEQ + i0 + g * 4]) = f1;
    }
}

// ---------------- Combine split-K partials -> bf16 Q, K, Vt. grid 1536, block 256.
// blocks [0,1024): Q,K rows; [1024,1536): Vt.
__global__ __launch_bounds__(256) void combine_kernel(
    const float* __restrict__ Pqk, const float* __restrict__ Pv,
    short* __restrict__ Qws, short* __restrict__ Kws, short* __restrict__ Vtws)
{
    const int b = blockIdx.x;
    if (b < 1024) {
        int tid = b * 256 + threadIdx.x;          // 262144 threads, 4 elems each
        int mat = tid >> 17;                      // 131072 per matrix
        int idx4 = (tid & 131071) * 4;
        const float* p0 = Pqk + ((size_t)(mat * 2 + 0) * SEQ) * DH;
        const float* p1 = Pqk + ((size_t)(mat * 2 + 1) * SEQ) * DH;
        float4 a = *reinterpret_cast<const float4*>(p0 + idx4);
        float4 c = *reinterpret_cast<const float4*>(p1 + idx4);
        short4v o = { f2bf(a.x + c.x), f2bf(a.y + c.y), f2bf(a.z + c.z), f2bf(a.w + c.w) };
        short* outp = (mat == 0) ? Qws : Kws;
        *reinterpret_cast<short4v*>(outp + idx4) = o;
    } else {
        int tid = (b - 1024) * 256 + threadIdx.x; // 131072 threads, 4 elems each
        int idx4 = tid * 4;
        float4 a = *reinterpret_cast<const float4*>(Pv + idx4);
        float4 c = *reinterpret_cast<const float4*>(Pv + (size_t)DH * SEQ + idx4);
        short4v o = { f2bf(a.x + c.x), f2bf(a.y + c.y), f2bf(a.z + c.z), f2bf(a.w + c.w) };
        *reinterpret_cast<short4v*>(Vtws + idx4) = o;
    }
}

// ---------------- Flash attention, NS-way key split (NS = gridDim.y).
// grid (256, NS), block 64 (one wave). q-tile = 16 rows, j-tile = 64 keys.
__global__ __launch_bounds__(64) void flash_kernel(
    const short* __restrict__ Qws, const short* __restrict__ Kws, const short* __restrict__ Vtws,
    float* __restrict__ Opart, float* __restrict__ mpart, float* __restrict__ lpart)
{
    const int i  = blockIdx.x;
    const int h  = blockIdx.y;
    const int NS = gridDim.y;
    const int i0 = i * 16;
    const int lane = threadIdx.x;
    const int g = lane >> 4, c16 = lane & 15;

    __shared__ short Slds[16][72];

    bf16x8 qf[4];
    #pragma unroll
    for (int kk = 0; kk < 4; kk++)
        qf[kk] = *reinterpret_cast<const bf16x8*>(Qws + (size_t)(i0 + c16) * DH + kk * 32 + g * 8);

    float m[4], lsum[4];
    f32x4 O[8];
    #pragma unroll
    for (int r = 0; r < 4; r++) { m[r] = -__builtin_inff(); lsum[r] = 0.f; }
    #pragma unroll
    for (int c = 0; c < 8; c++) O[c] = (f32x4){0.f, 0.f, 0.f, 0.f};

    const int njt = i / 4 + 1;
    const float C = 0.03188448666f;            // log2(e)/sqrt(2048)

    for (int jt = h; jt < njt; jt += NS) {
        const int j0 = jt * 64;
        f32x4 S[4];
        #pragma unroll
        for (int t = 0; t < 4; t++) S[t] = (f32x4){0.f, 0.f, 0.f, 0.f};
        #pragma unroll
        for (int kk = 0; kk < 4; kk++) {
            #pragma unroll
            for (int t = 0; t < 4; t++) {
                bf16x8 kf = *reinterpret_cast<const bf16x8*>(
                    Kws + (size_t)(j0 + t * 16 + c16) * DH + kk * 32 + g * 8);
                S[t] = __builtin_amdgcn_mfma_f32_16x16x32_bf16(qf[kk], kf, S[t], 0, 0, 0);
            }
        }
        float s2[4][4];
        #pragma unroll
        for (int t = 0; t < 4; t++) {
            int key = j0 + t * 16 + c16;
            #pragma unroll
            for (int r = 0; r < 4; r++) {
                int q = i0 + g * 4 + r;
                s2[t][r] = (key > q) ? -__builtin_inff() : S[t][r] * C;
            }
        }
        float mnew[4], alpha[4];
        #pragma unroll
        for (int r = 0; r < 4; r++) {
            float rm = fmaxf(fmaxf(s2[0][r], s2[1][r]), fmaxf(s2[2][r], s2[3][r]));
            rm = fmaxf(rm, __shfl_xor(rm, 1));
            rm = fmaxf(rm, __shfl_xor(rm, 2));
            rm = fmaxf(rm, __shfl_xor(rm, 4));
            rm = fmaxf(rm, __shfl_xor(rm, 8));
            mnew[r] = fmaxf(m[r], rm);
            alpha[r] = exp2f(m[r] - mnew[r]);
            m[r] = mnew[r];
        }
        #pragma unroll
        for (int r = 0; r < 4; r++) {
            float ps = 0.f;
            #pragma unroll
            for (int t = 0; t < 4; t++) {
                float p = exp2f(s2[t][r] - mnew[r]);
                ps += p;
                Slds[g * 4 + r][t * 16 + c16] = f2bf(p);
            }
            ps += __shfl_xor(ps, 1);
            ps += __shfl_xor(ps, 2);
            ps += __shfl_xor(ps, 4);
            ps += __shfl_xor(ps, 8);
            lsum[r] = lsum[r] * alpha[r] + ps;
            #pragma unroll
            for (int c = 0; c < 8; c++) O[c][r] *= alpha[r];
        }
        #pragma unroll
        for (int kk2 = 0; kk2 < 2; kk2++) {
            bf16x8 pf = *reinterpret_cast<const bf16x8*>(&Slds[c16][kk2 * 32 + g * 8]);
            #pragma unroll
            for (int c = 0; c < 8; c++) {
                bf16x8 vf = *reinterpret_cast<const bf16x8*>(
                    Vtws + (size_t)(c * 16 + c16) * SEQ + j0 + kk2 * 32 + g * 8);
                O[c] = __builtin_amdgcn_mfma_f32_16x16x32_bf16(pf, vf, O[c], 0, 0, 0);
            }
        }
    }
    #pragma unroll
    for (int c = 0; c < 8; c++) {
        int col = c * 16 + c16;
        #pragma unroll
        for (int r = 0; r < 4; r++)
            Opart[((size_t)h * SEQ + i0 + g * 4 + r) * DH + col] = O[c][r];
    }
    if (c16 == 0) {
        #pragma unroll
        for (int r = 0; r < 4; r++) {
            mpart[h * SEQ + i0 + g * 4 + r] = m[r];
            lpart[h * SEQ + i0 + g * 4 + r] = lsum[r];
        }
    }
}

// ---------------- Merge NS split partials. grid 2048, block 256 (2 rows/block).
__global__ __launch_bounds__(256) void merge_kernel(
    const float* __restrict__ Opart, const float* __restrict__ mpart, const float* __restrict__ lpart,
    float* __restrict__ out, int NS)
{
    const int row = blockIdx.x * 2 + (threadIdx.x >> 7);
    const int col = threadIdx.x & 127;
    float mh[16];
    float M = -__builtin_inff();
    for (int hh = 0; hh < NS; hh++) {
        mh[hh] = mpart[hh * SEQ + row];
        M = fmaxf(M, mh[hh]);
    }
    float denom = 0.f, num = 0.f;
    for (int hh = 0; hh < NS; hh++) {
        float wgt = exp2f(mh[hh] - M);
        denom += lpart[hh * SEQ + row] * wgt;
        num   += Opart[((size_t)hh * SEQ + row) * DH + col] * wgt;
    }
    out[(size_t)row * DH + col] = num / denom;
}

extern "C" void kernel_launch(void* const* d_in, const int* in_sizes, int n_in,
                              void* d_out, int out_size, void* d_ws, size_t ws_size,
                              hipStream_t stream) {
    const float* inq = (const float*)d_in[0];
    const float* ink = (const float*)d_in[1];
    const float* inv = (const float*)d_in[2];
    const float* wq  = (const float*)d_in[3];
    const float* bq  = (const float*)d_in[4];
    const float* wk  = (const float*)d_in[5];
    const float* bk  = (const float*)d_in[6];
    const float* wv  = (const float*)d_in[7];
    const float* bv  = (const float*)d_in[8];

    const int NS = (ws_size >= (size_t)36 * 1024 * 1024) ? 16 : 8;

    char* ws = (char*)d_ws;
    short* Qws   = (short*)(ws);                         // [0, 1 MB)
    short* Kws   = (short*)(ws + (1u << 20));            // [1, 2 MB)
    short* Vtws  = (short*)(ws + (2u << 20));            // [2, 3 MB)  ([128][4096])
    short* Wbf   = (short*)(ws + (3u << 20));            // [3, 4.5 MB) bf16 W (proj-only)
    float* Pqk   = (float*)(ws + 4718592);               // [4.5, 12.5 MB) [2 mat][2 s][4096][128]
    float* Pv    = (float*)(ws + 13107200);              // [12.5, 16.5 MB) [2 s][128][4096]
    float* Opart = (float*)(ws + (3u << 20));            // aliases Wbf/Pqk/Pv (dead by flash)
    float* mpart = (float*)(ws + (3u << 20) + (size_t)NS * SEQ * DH * 4);
    float* lpart = mpart + (size_t)NS * SEQ;

    convw_kernel<<<768, 256, 0, stream>>>(wq, wk, wv, Wbf);
    proj_kernel<<<dim3(256, 3, 2), 256, 0, stream>>>(inq, ink, inv, Wbf, bq, bk, bv, Pqk, Pv);
    combine_kernel<<<1536, 256, 0, stream>>>(Pqk, Pv, Qws, Kws, Vtws);
    flash_kernel<<<dim3(256, NS), 64, 0, stream>>>(Qws, Kws, Vtws, Opart, mpart, lpart);
    merge_kernel<<<2048, 256, 0, stream>>>(Opart, mpart, lpart, (float*)d_out, NS);
}

// Round 5
// 214.517 us; speedup vs baseline: 1.2182x; 1.1414x over previous
//
#include <hip/hip_runtime.h>

#define SEQ 4096
#define DM  2048
#define DH  128

typedef __attribute__((ext_vector_type(8))) short bf16x8;
typedef __attribute__((ext_vector_type(4))) short short4v;
typedef __attribute__((ext_vector_type(4))) float f32x4;

__device__ inline short f2bf(float f) {
    union { float f; unsigned u; } x; x.f = f;
    unsigned r = x.u + 0x7fffu + ((x.u >> 16) & 1u);
    return (short)(r >> 16);
}

// ---------------- W fp32 -> bf16 pre-convert. grid 768, block 256. Wbf[3][128][2048]
__global__ __launch_bounds__(256) void convw_kernel(
    const float* __restrict__ wq, const float* __restrict__ wk, const float* __restrict__ wv,
    short* __restrict__ Wbf)
{
    int idx = blockIdx.x * 256 + threadIdx.x;
    int mat = idx >> 16;
    int off = (idx & 65535) * 4;
    const float* W = (mat == 0) ? wq : (mat == 1) ? wk : wv;
    float4 v = *reinterpret_cast<const float4*>(W + off);
    short4v s = { f2bf(v.x), f2bf(v.y), f2bf(v.z), f2bf(v.w) };
    *reinterpret_cast<short4v*>(Wbf + (size_t)mat * DH * DM + off) = s;
}

// ---------------- Projection, split-K x2. grid (128, 3, 2), block 256 (4 waves).
// Block tile: 32 rows x 128 cols, K-range 1024, BK=64 (16 chunks).
// Depth-4 register prefetch for BOTH A (fp32, cvt on LDS write) and W (bf16),
// issue order W-then-A each iter so a chunk's s_waitcnt only drains loads
// issued 4 iterations earlier (in-order vmcnt completion).
__global__ __launch_bounds__(256) void proj_kernel(
    const float* __restrict__ inq, const float* __restrict__ ink, const float* __restrict__ inv,
    const short* __restrict__ Wbf,
    const float* __restrict__ bq, const float* __restrict__ bk, const float* __restrict__ bv,
    float* __restrict__ Pqk, float* __restrict__ Pv)
{
    const int mat = blockIdx.y;
    const int s   = blockIdx.z;
    const float* A    = (mat == 0) ? inq : (mat == 1) ? ink : inv;
    const float* bias = (mat == 0) ? bq : (mat == 1) ? bk : bv;

    const int tid  = threadIdx.x;
    const int lane = tid & 63;
    const int w    = tid >> 6;
    const int g    = lane >> 4;
    const int c16  = lane & 15;
    const int i0   = blockIdx.x * 32;
    const int kb   = s * 1024;

    __shared__ short Alds[32][72];    // 32 rows x 64 k bf16, padded (2-way = free)
    __shared__ short Wlds[128][72];   // 128 w-rows x 64 k bf16, padded

    // A stager: thread t -> row t>>3 (0..31), cols (t&7)*8 (2 float4)
    const int ar = tid >> 3, ac = (tid & 7) * 8;
    const float* Aload = A + (size_t)(i0 + ar) * DM + kb + ac;
    // W stager: thread t -> row t>>1 (0..127), cols (t&1)*32 (4 bf16x8)
    const int wr = tid >> 1, wc = (tid & 1) * 32;
    const short* Wload = Wbf + (size_t)mat * DH * DM + (size_t)wr * DM + kb + wc;

    f32x4 acc[4];
    #pragma unroll
    for (int n = 0; n < 4; n++) acc[n] = (f32x4){0.f, 0.f, 0.f, 0.f};

    float4  abuf[4][2];
    bf16x8  wbuf[4][4];

    // prologue: fill depth-4 pipeline (W first, then A, per chunk)
    #pragma unroll
    for (int d = 0; d < 4; d++) {
        #pragma unroll
        for (int j = 0; j < 4; j++)
            wbuf[d][j] = *reinterpret_cast<const bf16x8*>(Wload + d * 64 + j * 8);
        abuf[d][0] = *reinterpret_cast<const float4*>(Aload + d * 64);
        abuf[d][1] = *reinterpret_cast<const float4*>(Aload + d * 64 + 4);
    }

    const int arow = (w >> 1) * 16 + c16;         // A frag row for this wave
    const int wbase = (w & 1) * 64;               // W col-half for this wave

    #pragma unroll
    for (int c = 0; c < 16; c++) {
        const int d = c & 3;
        // write chunk c from regs into LDS (waits only loads issued 4 iters ago)
        {
            short4v s0 = { f2bf(abuf[d][0].x), f2bf(abuf[d][0].y),
                           f2bf(abuf[d][0].z), f2bf(abuf[d][0].w) };
            short4v s1 = { f2bf(abuf[d][1].x), f2bf(abuf[d][1].y),
                           f2bf(abuf[d][1].z), f2bf(abuf[d][1].w) };
            *reinterpret_cast<short4v*>(&Alds[ar][ac])     = s0;
            *reinterpret_cast<short4v*>(&Alds[ar][ac + 4]) = s1;
            #pragma unroll
            for (int j = 0; j < 4; j++)
                *reinterpret_cast<bf16x8*>(&Wlds[wr][wc + j * 8]) = wbuf[d][j];
        }
        // issue chunk c+4 loads (W first, then A)
        if (c + 4 < 16) {
            #pragma unroll
            for (int j = 0; j < 4; j++)
                wbuf[d][j] = *reinterpret_cast<const bf16x8*>(Wload + (c + 4) * 64 + j * 8);
            abuf[d][0] = *reinterpret_cast<const float4*>(Aload + (c + 4) * 64);
            abuf[d][1] = *reinterpret_cast<const float4*>(Aload + (c + 4) * 64 + 4);
        }
        __syncthreads();
        #pragma unroll
        for (int kk = 0; kk < 2; kk++) {
            bf16x8 af = *reinterpret_cast<const bf16x8*>(&Alds[arow][kk * 32 + g * 8]);
            #pragma unroll
            for (int n = 0; n < 4; n++) {
                bf16x8 wf = *reinterpret_cast<const bf16x8*>(
                    &Wlds[wbase + n * 16 + c16][kk * 32 + g * 8]);
                acc[n] = __builtin_amdgcn_mfma_f32_16x16x32_bf16(af, wf, acc[n], 0, 0, 0);
            }
        }
        __syncthreads();
    }

    const int row0 = i0 + (w >> 1) * 16 + g * 4;
    if (mat < 2) {
        float* outp = Pqk + ((size_t)(mat * 2 + s) * SEQ) * DH;
        #pragma unroll
        for (int n = 0; n < 4; n++) {
            int col = wbase + n * 16 + c16;
            float b0 = (s == 0) ? bias[col] : 0.f;
            #pragma unroll
            for (int r = 0; r < 4; r++)
                outp[(size_t)(row0 + r) * DH + col] = acc[n][r] + b0;
        }
    } else {
        float* outp = Pv + (size_t)s * DH * SEQ;
        #pragma unroll
        for (int n = 0; n < 4; n++) {
            int col = wbase + n * 16 + c16;
            float b0 = (s == 0) ? bias[col] : 0.f;
            float4 f = { acc[n][0] + b0, acc[n][1] + b0, acc[n][2] + b0, acc[n][3] + b0 };
            *reinterpret_cast<float4*>(&outp[(size_t)col * SEQ + row0]) = f;
        }
    }
}

// ---------------- Combine split-K partials -> bf16 Q, K, Vt. grid 1536, block 256.
__global__ __launch_bounds__(256) void combine_kernel(
    const float* __restrict__ Pqk, const float* __restrict__ Pv,
    short* __restrict__ Qws, short* __restrict__ Kws, short* __restrict__ Vtws)
{
    const int b = blockIdx.x;
    if (b < 1024) {
        int tid = b * 256 + threadIdx.x;
        int mat = tid >> 17;
        int idx4 = (tid & 131071) * 4;
        const float* p0 = Pqk + ((size_t)(mat * 2 + 0) * SEQ) * DH;
        const float* p1 = Pqk + ((size_t)(mat * 2 + 1) * SEQ) * DH;
        float4 a = *reinterpret_cast<const float4*>(p0 + idx4);
        float4 c = *reinterpret_cast<const float4*>(p1 + idx4);
        short4v o = { f2bf(a.x + c.x), f2bf(a.y + c.y), f2bf(a.z + c.z), f2bf(a.w + c.w) };
        short* outp = (mat == 0) ? Qws : Kws;
        *reinterpret_cast<short4v*>(outp + idx4) = o;
    } else {
        int tid = (b - 1024) * 256 + threadIdx.x;
        int idx4 = tid * 4;
        float4 a = *reinterpret_cast<const float4*>(Pv + idx4);
        float4 c = *reinterpret_cast<const float4*>(Pv + (size_t)DH * SEQ + idx4);
        short4v o = { f2bf(a.x + c.x), f2bf(a.y + c.y), f2bf(a.z + c.z), f2bf(a.w + c.w) };
        *reinterpret_cast<short4v*>(Vtws + idx4) = o;
    }
}

// ---------------- Flash attention, NS-way key split (NS = gridDim.y).
// grid (256, NS), block 64 (one wave). q-tile = 16 rows, j-tile = 64 keys.
__global__ __launch_bounds__(64) void flash_kernel(
    const short* __restrict__ Qws, const short* __restrict__ Kws, const short* __restrict__ Vtws,
    float* __restrict__ Opart, float* __restrict__ mpart, float* __restrict__ lpart)
{
    const int i  = blockIdx.x;
    const int h  = blockIdx.y;
    const int NS = gridDim.y;
    const int i0 = i * 16;
    const int lane = threadIdx.x;
    const int g = lane >> 4, c16 = lane & 15;

    __shared__ short Slds[16][72];

    bf16x8 qf[4];
    #pragma unroll
    for (int kk = 0; kk < 4; kk++)
        qf[kk] = *reinterpret_cast<const bf16x8*>(Qws + (size_t)(i0 + c16) * DH + kk * 32 + g * 8);

    float m[4], lsum[4];
    f32x4 O[8];
    #pragma unroll
    for (int r = 0; r < 4; r++) { m[r] = -__builtin_inff(); lsum[r] = 0.f; }
    #pragma unroll
    for (int c = 0; c < 8; c++) O[c] = (f32x4){0.f, 0.f, 0.f, 0.f};

    const int njt = i / 4 + 1;
    const float C = 0.03188448666f;            // log2(e)/sqrt(2048)

    for (int jt = h; jt < njt; jt += NS) {
        const int j0 = jt * 64;
        f32x4 S[4];
        #pragma unroll
        for (int t = 0; t < 4; t++) S[t] = (f32x4){0.f, 0.f, 0.f, 0.f};
        #pragma unroll
        for (int kk = 0; kk < 4; kk++) {
            #pragma unroll
            for (int t = 0; t < 4; t++) {
                bf16x8 kf = *reinterpret_cast<const bf16x8*>(
                    Kws + (size_t)(j0 + t * 16 + c16) * DH + kk * 32 + g * 8);
                S[t] = __builtin_amdgcn_mfma_f32_16x16x32_bf16(qf[kk], kf, S[t], 0, 0, 0);
            }
        }
        float s2[4][4];
        #pragma unroll
        for (int t = 0; t < 4; t++) {
            int key = j0 + t * 16 + c16;
            #pragma unroll
            for (int r = 0; r < 4; r++) {
                int q = i0 + g * 4 + r;
                s2[t][r] = (key > q) ? -__builtin_inff() : S[t][r] * C;
            }
        }
        float mnew[4], alpha[4];
        #pragma unroll
        for (int r = 0; r < 4; r++) {
            float rm = fmaxf(fmaxf(s2[0][r], s2[1][r]), fmaxf(s2[2][r], s2[3][r]));
            rm = fmaxf(rm, __shfl_xor(rm, 1));
            rm = fmaxf(rm, __shfl_xor(rm, 2));
            rm = fmaxf(rm, __shfl_xor(rm, 4));
            rm = fmaxf(rm, __shfl_xor(rm, 8));
            mnew[r] = fmaxf(m[r], rm);
            alpha[r] = exp2f(m[r] - mnew[r]);
            m[r] = mnew[r];
        }
        #pragma unroll
        for (int r = 0; r < 4; r++) {
            float ps = 0.f;
            #pragma unroll
            for (int t = 0; t < 4; t++) {
                float p = exp2f(s2[t][r] - mnew[r]);
                ps += p;
                Slds[g * 4 + r][t * 16 + c16] = f2bf(p);
            }
            ps += __shfl_xor(ps, 1);
            ps += __shfl_xor(ps, 2);
            ps += __shfl_xor(ps, 4);
            ps += __shfl_xor(ps, 8);
            lsum[r] = lsum[r] * alpha[r] + ps;
            #pragma unroll
            for (int c = 0; c < 8; c++) O[c][r] *= alpha[r];
        }
        #pragma unroll
        for (int kk2 = 0; kk2 < 2; kk2++) {
            bf16x8 pf = *reinterpret_cast<const bf16x8*>(&Slds[c16][kk2 * 32 + g * 8]);
            #pragma unroll
            for (int c = 0; c < 8; c++) {
                bf16x8 vf = *reinterpret_cast<const bf16x8*>(
                    Vtws + (size_t)(c * 16 + c16) * SEQ + j0 + kk2 * 32 + g * 8);
                O[c] = __builtin_amdgcn_mfma_f32_16x16x32_bf16(pf, vf, O[c], 0, 0, 0);
            }
        }
    }
    #pragma unroll
    for (int c = 0; c < 8; c++) {
        int col = c * 16 + c16;
        #pragma unroll
        for (int r = 0; r < 4; r++)
            Opart[((size_t)h * SEQ + i0 + g * 4 + r) * DH + col] = O[c][r];
    }
    if (c16 == 0) {
        #pragma unroll
        for (int r = 0; r < 4; r++) {
            mpart[h * SEQ + i0 + g * 4 + r] = m[r];
            lpart[h * SEQ + i0 + g * 4 + r] = lsum[r];
        }
    }
}

// ---------------- Merge NS split partials. grid 2048, block 256 (2 rows/block).
__global__ __launch_bounds__(256) void merge_kernel(
    const float* __restrict__ Opart, const float* __restrict__ mpart, const float* __restrict__ lpart,
    float* __restrict__ out, int NS)
{
    const int row = blockIdx.x * 2 + (threadIdx.x >> 7);
    const int col = threadIdx.x & 127;
    float mh[16];
    float M = -__builtin_inff();
    for (int hh = 0; hh < NS; hh++) {
        mh[hh] = mpart[hh * SEQ + row];
        M = fmaxf(M, mh[hh]);
    }
    float denom = 0.f, num = 0.f;
    for (int hh = 0; hh < NS; hh++) {
        float wgt = exp2f(mh[hh] - M);
        denom += lpart[hh * SEQ + row] * wgt;
        num   += Opart[((size_t)hh * SEQ + row) * DH + col] * wgt;
    }
    out[(size_t)row * DH + col] = num / denom;
}

extern "C" void kernel_launch(void* const* d_in, const int* in_sizes, int n_in,
                              void* d_out, int out_size, void* d_ws, size_t ws_size,
                              hipStream_t stream) {
    const float* inq = (const float*)d_in[0];
    const float* ink = (const float*)d_in[1];
    const float* inv = (const float*)d_in[2];
    const float* wq  = (const float*)d_in[3];
    const float* bq  = (const float*)d_in[4];
    const float* wk  = (const float*)d_in[5];
    const float* bk  = (const float*)d_in[6];
    const float* wv  = (const float*)d_in[7];
    const float* bv  = (const float*)d_in[8];

    const int NS = (ws_size >= (size_t)36 * 1024 * 1024) ? 16 : 8;

    char* ws = (char*)d_ws;
    short* Qws   = (short*)(ws);                         // [0, 1 MB)
    short* Kws   = (short*)(ws + (1u << 20));            // [1, 2 MB)
    short* Vtws  = (short*)(ws + (2u << 20));            // [2, 3 MB)  ([128][4096])
    short* Wbf   = (short*)(ws + (3u << 20));            // [3, 4.5 MB) bf16 W (proj-only)
    float* Pqk   = (float*)(ws + 4718592);               // [4.5, 12.5 MB) [2 mat][2 s][4096][128]
    float* Pv    = (float*)(ws + 13107200);              // [12.5, 16.5 MB) [2 s][128][4096]
    float* Opart = (float*)(ws + (3u << 20));            // aliases Wbf/Pqk/Pv (dead by flash)
    float* mpart = (float*)(ws + (3u << 20) + (size_t)NS * SEQ * DH * 4);
    float* lpart = mpart + (size_t)NS * SEQ;

    convw_kernel<<<768, 256, 0, stream>>>(wq, wk, wv, Wbf);
    proj_kernel<<<dim3(128, 3, 2), 256, 0, stream>>>(inq, ink, inv, Wbf, bq, bk, bv, Pqk, Pv);
    combine_kernel<<<1536, 256, 0, stream>>>(Pqk, Pv, Qws, Kws, Vtws);
    flash_kernel<<<dim3(256, NS), 64, 0, stream>>>(Qws, Kws, Vtws, Opart, mpart, lpart);
    merge_kernel<<<2048, 256, 0, stream>>>(Opart, mpart, lpart, (float*)d_out, NS);
}